// Round 2
// baseline (116.291 us; speedup 1.0000x reference)
//
#include <hip/hip_runtime.h>
#include <hip/hip_bf16.h>

// CapsuleNet dynamic routing, fused per-sample. ALL fp32 I/O:
// x: f32 [8192, 32, 8], W: f32 [32, 8, 256], out: f32 [8192, 16, 16].
// One block = S samples; thread t = (nc = t>>4, dc = t&15) owns output column
// k = t. u_hat kept entirely in registers (uh[S][32]); routing in LDS.
// W is pre-transposed to bf16 Wt[ic][k][id] (one dwordx4 per (ic,k)) to halve
// the per-block W traffic (every block reads all of W; routing couples all nc).

#define S 4   // samples per block: uh regs = 32*S = 128 VGPR; launch_bounds(256,2)

__device__ __forceinline__ float bflo(unsigned u) { return __uint_as_float(u << 16); }
__device__ __forceinline__ float bfhi(unsigned u) { return __uint_as_float(u & 0xffff0000u); }

// W[ic][id][k] (f32) -> Wt[ic][k][id] (bf16), 65536 elements
__global__ __launch_bounds__(256) void wt_kernel(const float* __restrict__ W,
                                                 unsigned short* __restrict__ Wt) {
  int o  = blockIdx.x * 256 + threadIdx.x;
  int ic = o >> 11;
  int k  = (o >> 3) & 255;
  int id = o & 7;
  Wt[o] = (unsigned short)(__bfloat16_as_ushort(__float2bfloat16(W[(ic * 8 + id) * 256 + k])));
}

__device__ __forceinline__ float squash_val(float o) {
  // reduce o^2 over the 16 dc lanes (lanes sharing nc are contiguous 16-lane groups)
  float s2 = o * o;
  s2 += __shfl_xor(s2, 1);
  s2 += __shfl_xor(s2, 2);
  s2 += __shfl_xor(s2, 4);
  s2 += __shfl_xor(s2, 8);
  s2 += 1e-7f;
  return o * (s2 / ((1.f + s2) * sqrtf(s2)));
}

// b[nc][ic] (=/+=) sum_dc v*uh[ic]  via transpose-reduction over the 16 dc
// lanes: 15 shuffles reduce 16 ic-values; lane dc lands the sum for ic=icb+dc.
template <bool ASSIGN>
__device__ __forceinline__ void b_update(float v, const float* uhs, int dc, float* bp) {
#pragma unroll
  for (int icb = 0; icb < 32; icb += 16) {
    float a[16];
#pragma unroll
    for (int j = 0; j < 16; ++j) a[j] = v * uhs[icb + j];
    float b8[8];
    const bool u8 = (dc & 8) != 0;
#pragma unroll
    for (int j = 0; j < 8; ++j) {
      float send = u8 ? a[j] : a[j + 8];
      float recv = __shfl_xor(send, 8);
      b8[j] = (u8 ? a[j + 8] : a[j]) + recv;
    }
    float c4[4];
    const bool u4 = (dc & 4) != 0;
#pragma unroll
    for (int j = 0; j < 4; ++j) {
      float send = u4 ? b8[j] : b8[j + 4];
      float recv = __shfl_xor(send, 4);
      c4[j] = (u4 ? b8[j + 4] : b8[j]) + recv;
    }
    float d2[2];
    const bool u2 = (dc & 2) != 0;
#pragma unroll
    for (int j = 0; j < 2; ++j) {
      float send = u2 ? c4[j] : c4[j + 2];
      float recv = __shfl_xor(send, 2);
      d2[j] = (u2 ? c4[j + 2] : c4[j]) + recv;
    }
    const bool u1 = (dc & 1) != 0;
    float send = u1 ? d2[0] : d2[1];
    float recv = __shfl_xor(send, 1);
    float e = (u1 ? d2[1] : d2[0]) + recv;
    if (ASSIGN) bp[icb + dc] = e;
    else        bp[icb + dc] += e;
  }
}

__global__ __launch_bounds__(256, 2) void caps_kernel(const float* __restrict__ x,
                                                      const uint4* __restrict__ Wt4,
                                                      float* __restrict__ out) {
  const int t  = threadIdx.x;
  const int nc = t >> 4;
  const int dc = t & 15;
  const int s0 = blockIdx.x * S;

  __shared__ float b_lds[S][16][33];  // +1 pad: softmax column reads conflict-free
  __shared__ float c_lds[S][16][36];  // +4 pad: float4 rows on distinct banks per nc

  float uh[S][32];

  // ---- u_hat: uh[s][ic] = sum_id u[s][ic][id] * W[ic][id][k] ----
#pragma unroll
  for (int ic = 0; ic < 32; ++ic) {
    uint4 wv = Wt4[ic * 256 + t];  // 8 bf16 weights, coalesced dwordx4
    float w0 = bflo(wv.x), w1 = bfhi(wv.x);
    float w2 = bflo(wv.y), w3 = bfhi(wv.y);
    float w4 = bflo(wv.z), w5 = bfhi(wv.z);
    float w6 = bflo(wv.w), w7 = bfhi(wv.w);
#pragma unroll
    for (int s = 0; s < S; ++s) {
      const float* up = &x[(s0 + s) * 256 + ic * 8];  // wave-uniform -> s_load
      float acc = up[0] * w0;
      acc = fmaf(up[1], w1, acc);
      acc = fmaf(up[2], w2, acc);
      acc = fmaf(up[3], w3, acc);
      acc = fmaf(up[4], w4, acc);
      acc = fmaf(up[5], w5, acc);
      acc = fmaf(up[6], w6, acc);
      acc = fmaf(up[7], w7, acc);
      uh[s][ic] = acc;
    }
  }

  // ---- routing round 0: b = 0 => c = 1/16 uniformly ----
#pragma unroll
  for (int s = 0; s < S; ++s) {
    float o = 0.f;
#pragma unroll
    for (int ic = 0; ic < 32; ++ic) o += uh[s][ic];
    o *= 0.0625f;
    float v = squash_val(o);
    b_update<true>(v, uh[s], dc, &b_lds[s][nc][0]);  // b = delta (assign, b was 0)
  }
  __syncthreads();

  // ---- rounds 1, 2 ----
#pragma unroll
  for (int r = 1; r < 3; ++r) {
    if (t < S * 32) {  // softmax over nc for each (s, ic) column
      const int s = t >> 5, ic = t & 31;
      float m = -1e30f;
#pragma unroll
      for (int n = 0; n < 16; ++n) m = fmaxf(m, b_lds[s][n][ic]);
      float e[16];
      float sum = 0.f;
#pragma unroll
      for (int n = 0; n < 16; ++n) { e[n] = __expf(b_lds[s][n][ic] - m); sum += e[n]; }
      const float inv = 1.f / sum;
#pragma unroll
      for (int n = 0; n < 16; ++n) c_lds[s][n][ic] = e[n] * inv;
    }
    __syncthreads();
#pragma unroll
    for (int s = 0; s < S; ++s) {
      const float4* cp = (const float4*)&c_lds[s][nc][0];
      float o = 0.f;
#pragma unroll
      for (int j = 0; j < 8; ++j) {
        float4 cc = cp[j];
        o = fmaf(cc.x, uh[s][4 * j + 0], o);
        o = fmaf(cc.y, uh[s][4 * j + 1], o);
        o = fmaf(cc.z, uh[s][4 * j + 2], o);
        o = fmaf(cc.w, uh[s][4 * j + 3], o);
      }
      float v = squash_val(o);
      if (r == 2) {
        out[(s0 + s) * 256 + t] = v;
      } else {
        b_update<false>(v, uh[s], dc, &b_lds[s][nc][0]);
      }
    }
    __syncthreads();
  }
}

extern "C" void kernel_launch(void* const* d_in, const int* in_sizes, int n_in,
                              void* d_out, int out_size, void* d_ws, size_t ws_size,
                              hipStream_t stream) {
  const float* x = (const float*)d_in[0];
  const float* W = (const float*)d_in[1];
  unsigned short* Wt = (unsigned short*)d_ws;  // 128 KB scratch (bf16 W-transpose)

  wt_kernel<<<256, 256, 0, stream>>>(W, Wt);
  caps_kernel<<<8192 / S, 256, 0, stream>>>(x, (const uint4*)Wt, (float*)d_out);
}

// Round 3
// 113.501 us; speedup vs baseline: 1.0246x; 1.0246x over previous
//
#include <hip/hip_runtime.h>
#include <hip/hip_bf16.h>

// CapsuleNet dynamic routing, fused per-sample. fp32 I/O:
// x: f32 [8192, 32, 8], W: f32 [32, 8, 256], out: f32 [8192, 16, 16].
// One block = 2 samples packed as float2 lanes (.x = sample0, .y = sample1);
// thread t = (nc = t>>4, dc = t&15) owns output column k = t. u_hat in
// registers (float2 uh2[32] = 64 VGPR); routing state in LDS.
// W pre-transposed to bf16 Wt[ic][k][id]: one dwordx4 per (ic,k) thread-load.

#define S 2

__device__ __forceinline__ float bflo(unsigned u) { return __uint_as_float(u << 16); }
__device__ __forceinline__ float bfhi(unsigned u) { return __uint_as_float(u & 0xffff0000u); }

// W[ic][id][k] (f32) -> Wt[ic][k][id] (bf16), 65536 elements
__global__ __launch_bounds__(256) void wt_kernel(const float* __restrict__ W,
                                                 unsigned short* __restrict__ Wt) {
  int o  = blockIdx.x * 256 + threadIdx.x;
  int ic = o >> 11;
  int k  = (o >> 3) & 255;
  int id = o & 7;
  Wt[o] = (unsigned short)(__bfloat16_as_ushort(__float2bfloat16(W[(ic * 8 + id) * 256 + k])));
}

__device__ __forceinline__ float squash_val(float o) {
  // sum o^2 over the 16 dc lanes (nc groups are aligned 16-lane sub-blocks)
  float s2 = o * o;
  s2 += __shfl_xor(s2, 1);
  s2 += __shfl_xor(s2, 2);
  s2 += __shfl_xor(s2, 4);
  s2 += __shfl_xor(s2, 8);
  s2 += 1e-7f;
  return o * (s2 / ((1.f + s2) * sqrtf(s2)));
}

// b[nc][ic] (=/+=) sum_dc v*uh[ic] via butterfly transpose-reduction over the
// 16 dc lanes; lane dc lands the sums for ic = icb + dc. COMP picks sample.
template <bool ASSIGN, int COMP>
__device__ __forceinline__ void b_update(float v, const float2* uh2, int dc, float* bp) {
#pragma unroll
  for (int icb = 0; icb < 32; icb += 16) {
    float a[16];
#pragma unroll
    for (int j = 0; j < 16; ++j) a[j] = v * (COMP ? uh2[icb + j].y : uh2[icb + j].x);
    float b8[8];
    const bool u8 = (dc & 8) != 0;
#pragma unroll
    for (int j = 0; j < 8; ++j) {
      float send = u8 ? a[j] : a[j + 8];
      float recv = __shfl_xor(send, 8);
      b8[j] = (u8 ? a[j + 8] : a[j]) + recv;
    }
    float c4[4];
    const bool u4 = (dc & 4) != 0;
#pragma unroll
    for (int j = 0; j < 4; ++j) {
      float send = u4 ? b8[j] : b8[j + 4];
      float recv = __shfl_xor(send, 4);
      c4[j] = (u4 ? b8[j + 4] : b8[j]) + recv;
    }
    float d2[2];
    const bool u2 = (dc & 2) != 0;
#pragma unroll
    for (int j = 0; j < 2; ++j) {
      float send = u2 ? c4[j] : c4[j + 2];
      float recv = __shfl_xor(send, 2);
      d2[j] = (u2 ? c4[j + 2] : c4[j]) + recv;
    }
    const bool u1 = (dc & 1) != 0;
    float send = u1 ? d2[0] : d2[1];
    float recv = __shfl_xor(send, 1);
    float e = (u1 ? d2[1] : d2[0]) + recv;
    if (ASSIGN) bp[icb + dc] = e;
    else        bp[icb + dc] += e;
  }
}

__global__ __launch_bounds__(256, 4) void caps_kernel(const float* __restrict__ x,
                                                      const uint4* __restrict__ Wt4,
                                                      float* __restrict__ out) {
  const int t  = threadIdx.x;
  const int nc = t >> 4;
  const int dc = t & 15;
  const int s0 = blockIdx.x * S;

  __shared__ float  b_lds[S][16][33];   // +1 pad: column (over nc) reads conflict-free
  __shared__ float2 c2_lds[16][34];     // c for both samples packed; +2 pad per row

  float2 uh2[32];

  // ---- u_hat: uh2[ic] = { sum_id u_s0*W, sum_id u_s1*W } for column k = t ----
#pragma unroll
  for (int ic = 0; ic < 32; ++ic) {
    uint4 wv = Wt4[ic * 256 + t];  // 8 bf16 weights, coalesced dwordx4
    float w0 = bflo(wv.x), w1 = bfhi(wv.x);
    float w2 = bflo(wv.y), w3 = bfhi(wv.y);
    float w4 = bflo(wv.z), w5 = bfhi(wv.z);
    float w6 = bflo(wv.w), w7 = bfhi(wv.w);
    const float* u0 = &x[(s0 + 0) * 256 + ic * 8];  // block-uniform -> s_load
    const float* u1 = &x[(s0 + 1) * 256 + ic * 8];
    float ax = u0[0] * w0, ay = u1[0] * w0;
    ax = fmaf(u0[1], w1, ax);  ay = fmaf(u1[1], w1, ay);
    ax = fmaf(u0[2], w2, ax);  ay = fmaf(u1[2], w2, ay);
    ax = fmaf(u0[3], w3, ax);  ay = fmaf(u1[3], w3, ay);
    ax = fmaf(u0[4], w4, ax);  ay = fmaf(u1[4], w4, ay);
    ax = fmaf(u0[5], w5, ax);  ay = fmaf(u1[5], w5, ay);
    ax = fmaf(u0[6], w6, ax);  ay = fmaf(u1[6], w6, ay);
    ax = fmaf(u0[7], w7, ax);  ay = fmaf(u1[7], w7, ay);
    uh2[ic] = make_float2(ax, ay);
  }

  // ---- routing round 0: b = 0 => c = 1/16 ----
  {
    float o0 = 0.f, o1 = 0.f;
#pragma unroll
    for (int ic = 0; ic < 32; ++ic) { o0 += uh2[ic].x; o1 += uh2[ic].y; }
    o0 *= 0.0625f; o1 *= 0.0625f;
    float v0 = squash_val(o0);
    float v1 = squash_val(o1);
    b_update<true, 0>(v0, uh2, dc, &b_lds[0][nc][0]);
    b_update<true, 1>(v1, uh2, dc, &b_lds[1][nc][0]);
  }
  __syncthreads();

  // ---- rounds 1, 2 ----
#pragma unroll
  for (int r = 1; r < 3; ++r) {
    if (t < 32) {  // softmax over nc for column ic = t, both samples
      const int ic = t;
      float e0[16], e1[16];
      float m0 = -1e30f, m1 = -1e30f;
#pragma unroll
      for (int n = 0; n < 16; ++n) {
        m0 = fmaxf(m0, b_lds[0][n][ic]);
        m1 = fmaxf(m1, b_lds[1][n][ic]);
      }
      float sum0 = 0.f, sum1 = 0.f;
#pragma unroll
      for (int n = 0; n < 16; ++n) {
        e0[n] = __expf(b_lds[0][n][ic] - m0); sum0 += e0[n];
        e1[n] = __expf(b_lds[1][n][ic] - m1); sum1 += e1[n];
      }
      const float i0 = 1.f / sum0, i1 = 1.f / sum1;
#pragma unroll
      for (int n = 0; n < 16; ++n) c2_lds[n][ic] = make_float2(e0[n] * i0, e1[n] * i1);
    }
    __syncthreads();

    const float4* cp = (const float4*)&c2_lds[nc][0];  // {c0[ic],c1[ic],c0[ic+1],c1[ic+1]}
    float o0 = 0.f, o1 = 0.f;
#pragma unroll
    for (int j = 0; j < 16; ++j) {
      float4 cc = cp[j];
      o0 = fmaf(cc.x, uh2[2 * j + 0].x, o0);  o1 = fmaf(cc.y, uh2[2 * j + 0].y, o1);
      o0 = fmaf(cc.z, uh2[2 * j + 1].x, o0);  o1 = fmaf(cc.w, uh2[2 * j + 1].y, o1);
    }
    float v0 = squash_val(o0);
    float v1 = squash_val(o1);
    if (r == 2) {
      out[(s0 + 0) * 256 + t] = v0;
      out[(s0 + 1) * 256 + t] = v1;
    } else {
      b_update<false, 0>(v0, uh2, dc, &b_lds[0][nc][0]);
      b_update<false, 1>(v1, uh2, dc, &b_lds[1][nc][0]);
      __syncthreads();  // b complete before round-2 softmax reads it
    }
  }
}

extern "C" void kernel_launch(void* const* d_in, const int* in_sizes, int n_in,
                              void* d_out, int out_size, void* d_ws, size_t ws_size,
                              hipStream_t stream) {
  const float* x = (const float*)d_in[0];
  const float* W = (const float*)d_in[1];
  unsigned short* Wt = (unsigned short*)d_ws;  // 128 KB scratch (bf16 W-transpose)

  wt_kernel<<<256, 256, 0, stream>>>(W, Wt);
  caps_kernel<<<8192 / S, 256, 0, stream>>>(x, (const uint4*)Wt, (float*)d_out);
}

// Round 4
// 111.054 us; speedup vs baseline: 1.0472x; 1.0220x over previous
//
#include <hip/hip_runtime.h>
#include <hip/hip_bf16.h>

// CapsuleNet dynamic routing, fused per-sample. fp32 I/O:
// x: f32 [8192, 32, 8], W: f32 [32, 8, 256], out: f32 [8192, 16, 16].
// One block = 2 samples packed as the two components of v2f lanes;
// thread t = (nc = t>>4, dc = t&15) owns output column k = t.
// u_hat in registers (v2f uh2[32]); routing state in LDS.
// All hot math written 2-wide to form v_pk_fma_f32 / v_pk_mul_f32 (VOP3P).
// W pre-transposed to bf16 Wt[ic][k][id]: one dwordx4 per (ic,k) thread-load.

#define S 2

typedef float v2f __attribute__((ext_vector_type(2)));

__device__ __forceinline__ float bflo(unsigned u) { return __uint_as_float(u << 16); }
__device__ __forceinline__ float bfhi(unsigned u) { return __uint_as_float(u & 0xffff0000u); }

__device__ __forceinline__ v2f shfl_xor2(v2f v, int m) {
  v2f r;
  r.x = __shfl_xor(v.x, m);
  r.y = __shfl_xor(v.y, m);
  return r;
}

// W[ic][id][k] (f32) -> Wt[ic][k][id] (bf16), 65536 elements
__global__ __launch_bounds__(256) void wt_kernel(const float* __restrict__ W,
                                                 unsigned short* __restrict__ Wt) {
  int o  = blockIdx.x * 256 + threadIdx.x;
  int ic = o >> 11;
  int k  = (o >> 3) & 255;
  int id = o & 7;
  Wt[o] = (unsigned short)(__bfloat16_as_ushort(__float2bfloat16(W[(ic * 8 + id) * 256 + k])));
}

// squash over the 16 dc lanes, both samples at once (v2f = {s0, s1})
__device__ __forceinline__ v2f squash2(v2f o) {
  v2f s2 = o * o;
  s2 += shfl_xor2(s2, 1);
  s2 += shfl_xor2(s2, 2);
  s2 += shfl_xor2(s2, 4);
  s2 += shfl_xor2(s2, 8);
  s2 += (v2f){1e-7f, 1e-7f};
  v2f sc;
  sc.x = s2.x / ((1.f + s2.x) * sqrtf(s2.x));
  sc.y = s2.y / ((1.f + s2.y) * sqrtf(s2.y));
  return o * sc;
}

// b[nc][ic] (=/+=) sum_dc v*uh[ic], both samples packed, via butterfly
// transpose-reduction over the 16 dc lanes; lane dc lands ic = icb + dc.
template <bool ASSIGN>
__device__ __forceinline__ void b_update2(v2f v, const v2f* uh2, int dc,
                                          float* bp0, float* bp1) {
#pragma unroll
  for (int icb = 0; icb < 32; icb += 16) {
    v2f a[16];
#pragma unroll
    for (int j = 0; j < 16; ++j) a[j] = v * uh2[icb + j];  // pk_mul
    v2f b8[8];
    const bool u8 = (dc & 8) != 0;
#pragma unroll
    for (int j = 0; j < 8; ++j) {
      v2f send = u8 ? a[j] : a[j + 8];
      v2f recv = shfl_xor2(send, 8);
      b8[j] = (u8 ? a[j + 8] : a[j]) + recv;  // pk_add
    }
    v2f c4[4];
    const bool u4 = (dc & 4) != 0;
#pragma unroll
    for (int j = 0; j < 4; ++j) {
      v2f send = u4 ? b8[j] : b8[j + 4];
      v2f recv = shfl_xor2(send, 4);
      c4[j] = (u4 ? b8[j + 4] : b8[j]) + recv;
    }
    v2f d2[2];
    const bool u2 = (dc & 2) != 0;
#pragma unroll
    for (int j = 0; j < 2; ++j) {
      v2f send = u2 ? c4[j] : c4[j + 2];
      v2f recv = shfl_xor2(send, 2);
      d2[j] = (u2 ? c4[j + 2] : c4[j]) + recv;
    }
    const bool u1 = (dc & 1) != 0;
    v2f send = u1 ? d2[0] : d2[1];
    v2f recv = shfl_xor2(send, 1);
    v2f e = (u1 ? d2[1] : d2[0]) + recv;
    if (ASSIGN) { bp0[icb + dc] = e.x;  bp1[icb + dc] = e.y; }
    else        { bp0[icb + dc] += e.x; bp1[icb + dc] += e.y; }
  }
}

__global__ __launch_bounds__(256, 4) void caps_kernel(const float* __restrict__ x,
                                                      const uint4* __restrict__ Wt4,
                                                      float* __restrict__ out) {
  const int t  = threadIdx.x;
  const int nc = t >> 4;
  const int dc = t & 15;
  const int s0 = blockIdx.x * S;

  __shared__ float b_lds[S][16][33];          // +1 pad: nc-column reads conflict-free
  __shared__ __align__(16) float c_lds[16][72];  // c[n][2*ic+s]; 72 = 4-float-aligned rows

  v2f uh2[32];
  v2f o2 = (v2f){0.f, 0.f};

  // ---- u_hat: uh2[ic] = {sum_id u_s0*W, sum_id u_s1*W}; round-0 sum fused ----
  const v2f* xu0 = (const v2f*)(x + (s0 + 0) * 256);  // block-uniform -> s_load
  const v2f* xu1 = (const v2f*)(x + (s0 + 1) * 256);
#pragma unroll
  for (int ic = 0; ic < 32; ++ic) {
    uint4 wv = Wt4[ic * 256 + t];  // 8 bf16 weights, coalesced dwordx4
    v2f wp0 = (v2f){bflo(wv.x), bfhi(wv.x)};
    v2f wp1 = (v2f){bflo(wv.y), bfhi(wv.y)};
    v2f wp2 = (v2f){bflo(wv.z), bfhi(wv.z)};
    v2f wp3 = (v2f){bflo(wv.w), bfhi(wv.w)};
    v2f a0 = xu0[ic * 4 + 0] * wp0;  // pk_fma chain, sample 0 (id-paired)
    a0 = __builtin_elementwise_fma(xu0[ic * 4 + 1], wp1, a0);
    a0 = __builtin_elementwise_fma(xu0[ic * 4 + 2], wp2, a0);
    a0 = __builtin_elementwise_fma(xu0[ic * 4 + 3], wp3, a0);
    v2f a1 = xu1[ic * 4 + 0] * wp0;  // sample 1
    a1 = __builtin_elementwise_fma(xu1[ic * 4 + 1], wp1, a1);
    a1 = __builtin_elementwise_fma(xu1[ic * 4 + 2], wp2, a1);
    a1 = __builtin_elementwise_fma(xu1[ic * 4 + 3], wp3, a1);
    v2f u = (v2f){a0.x + a0.y, a1.x + a1.y};
    uh2[ic] = u;
    o2 += u;
  }

  // ---- routing round 0: b = 0 => c = 1/16 ----
  {
    v2f v = squash2(o2 * (v2f){0.0625f, 0.0625f});
    b_update2<true>(v, uh2, dc, &b_lds[0][nc][0], &b_lds[1][nc][0]);
  }
  __syncthreads();

  // ---- rounds 1, 2 ----
#pragma unroll
  for (int r = 1; r < 3; ++r) {
    if (t < 64) {  // softmax over nc; thread (s = t>>5, ic = t&31) owns one column
      const int s = t >> 5, ic = t & 31;
      float e[16];
      float m = -1e30f;
#pragma unroll
      for (int n = 0; n < 16; ++n) m = fmaxf(m, b_lds[s][n][ic]);
      float sum = 0.f;
#pragma unroll
      for (int n = 0; n < 16; ++n) { e[n] = __expf(b_lds[s][n][ic] - m); sum += e[n]; }
      const float inv = 1.f / sum;
#pragma unroll
      for (int n = 0; n < 16; ++n) c_lds[n][2 * ic + s] = e[n] * inv;
    }
    __syncthreads();

    const float4* cp = (const float4*)&c_lds[nc][0];  // {c0[2j],c1[2j],c0[2j+1],c1[2j+1]}
    v2f o = (v2f){0.f, 0.f};
#pragma unroll
    for (int j = 0; j < 16; ++j) {
      float4 cc = cp[j];
      o = __builtin_elementwise_fma((v2f){cc.x, cc.y}, uh2[2 * j + 0], o);
      o = __builtin_elementwise_fma((v2f){cc.z, cc.w}, uh2[2 * j + 1], o);
    }
    v2f v = squash2(o);
    if (r == 2) {
      out[(s0 + 0) * 256 + t] = v.x;
      out[(s0 + 1) * 256 + t] = v.y;
    } else {
      b_update2<false>(v, uh2, dc, &b_lds[0][nc][0], &b_lds[1][nc][0]);
      __syncthreads();  // b complete before round-2 softmax reads it
    }
  }
}

extern "C" void kernel_launch(void* const* d_in, const int* in_sizes, int n_in,
                              void* d_out, int out_size, void* d_ws, size_t ws_size,
                              hipStream_t stream) {
  const float* x = (const float*)d_in[0];
  const float* W = (const float*)d_in[1];
  unsigned short* Wt = (unsigned short*)d_ws;  // 128 KB scratch (bf16 W-transpose)

  wt_kernel<<<256, 256, 0, stream>>>(W, Wt);
  caps_kernel<<<8192 / S, 256, 0, stream>>>(x, (const uint4*)Wt, (float*)d_out);
}

// Round 5
// 107.045 us; speedup vs baseline: 1.0864x; 1.0374x over previous
//
#include <hip/hip_runtime.h>
#include <hip/hip_bf16.h>

// CapsuleNet dynamic routing, fused per-sample. fp32 I/O:
// x: f32 [8192, 32, 8], W: f32 [32, 8, 256], out: f32 [8192, 16, 16].
// One block = 2 samples packed as the two components of v2f lanes;
// thread t = (nc = t>>4, dc = t&15) owns output column k = t.
// u_hat in registers (v2f uh2[32]); routing state in LDS.
// Cross-lane exchanges use DPP (xor1/xor2/xor8 + mirrors) instead of
// ds_swizzle wherever an encoding exists; only xor4 stays on the DS pipe.
// W pre-transposed to bf16 Wt[ic][k][id]: one dwordx4 per (ic,k) thread-load.

#define S 2

typedef float v2f __attribute__((ext_vector_type(2)));

__device__ __forceinline__ float bflo(unsigned u) { return __uint_as_float(u << 16); }
__device__ __forceinline__ float bfhi(unsigned u) { return __uint_as_float(u & 0xffff0000u); }

// DPP cross-lane: value of `x` from lane (lane ^ k) within a 16-lane row.
// 0xB1 = quad_perm[1,0,3,2] (xor1)  0x4E = quad_perm[2,3,0,1] (xor2)
// 0x128 = row_ror:8 (xor8)  0x141 = row_half_mirror (xor7)  0x140 = row_mirror (xor15)
template <int CTRL>
__device__ __forceinline__ float dppf(float x) {
  return __builtin_bit_cast(float,
      __builtin_amdgcn_update_dpp(0, __builtin_bit_cast(int, x), CTRL, 0xF, 0xF, true));
}
template <int CTRL>
__device__ __forceinline__ v2f dpp2(v2f v) {
  v2f r;
  r.x = dppf<CTRL>(v.x);
  r.y = dppf<CTRL>(v.y);
  return r;
}
// xor4 has no DPP encoding: one ds_swizzle (BitMode: xor=4, and=0x1F)
__device__ __forceinline__ float swz4(float x) {
  return __builtin_bit_cast(float,
      __builtin_amdgcn_ds_swizzle(__builtin_bit_cast(int, x), 0x101F));
}
__device__ __forceinline__ v2f swz4_2(v2f v) {
  v2f r;
  r.x = swz4(v.x);
  r.y = swz4(v.y);
  return r;
}

// W[ic][id][k] (f32) -> Wt[ic][k][id] (bf16), 65536 elements
__global__ __launch_bounds__(256) void wt_kernel(const float* __restrict__ W,
                                                 unsigned short* __restrict__ Wt) {
  int o  = blockIdx.x * 256 + threadIdx.x;
  int ic = o >> 11;
  int k  = (o >> 3) & 255;
  int id = o & 7;
  Wt[o] = (unsigned short)(__bfloat16_as_ushort(__float2bfloat16(W[(ic * 8 + id) * 256 + k])));
}

// squash over the 16 dc lanes, both samples at once; DPP-only reduction.
__device__ __forceinline__ v2f squash2(v2f o) {
  v2f s2 = o * o;
  s2 += dpp2<0xB1>(s2);   // + lane^1  -> pair sums
  s2 += dpp2<0x4E>(s2);   // + lane^2  -> quad sums (quad-uniform)
  s2 += dpp2<0x141>(s2);  // + lane^7  -> 8-lane sums (uniform within 8)
  s2 += dpp2<0x140>(s2);  // + lane^15 -> 16-lane sums
  s2 += (v2f){1e-7f, 1e-7f};
  v2f sc;
  sc.x = s2.x * __builtin_amdgcn_rsqf(s2.x) * __builtin_amdgcn_rcpf(1.f + s2.x);
  sc.y = s2.y * __builtin_amdgcn_rsqf(s2.y) * __builtin_amdgcn_rcpf(1.f + s2.y);
  return o * sc;  // sqrt(s2)/(1+s2) * o
}

// b[nc][ic] (=/+=) sum_dc v*uh[ic], both samples packed, via butterfly
// transpose-reduction over the 16 dc lanes; lane dc lands ic = icb + dc.
// Levels 8/2/1 via DPP, level 4 via ds_swizzle.
template <bool ASSIGN>
__device__ __forceinline__ void b_update2(v2f v, const v2f* uh2, int dc,
                                          float* bp0, float* bp1) {
#pragma unroll
  for (int icb = 0; icb < 32; icb += 16) {
    v2f a[16];
#pragma unroll
    for (int j = 0; j < 16; ++j) a[j] = v * uh2[icb + j];  // pk_mul
    v2f b8[8];
    const bool u8 = (dc & 8) != 0;
#pragma unroll
    for (int j = 0; j < 8; ++j) {
      v2f send = u8 ? a[j] : a[j + 8];
      v2f recv = dpp2<0x128>(send);          // exchange with lane^8
      b8[j] = (u8 ? a[j + 8] : a[j]) + recv;
    }
    v2f c4[4];
    const bool u4 = (dc & 4) != 0;
#pragma unroll
    for (int j = 0; j < 4; ++j) {
      v2f send = u4 ? b8[j] : b8[j + 4];
      v2f recv = swz4_2(send);               // exchange with lane^4 (DS)
      c4[j] = (u4 ? b8[j + 4] : b8[j]) + recv;
    }
    v2f d2[2];
    const bool u2 = (dc & 2) != 0;
#pragma unroll
    for (int j = 0; j < 2; ++j) {
      v2f send = u2 ? c4[j] : c4[j + 2];
      v2f recv = dpp2<0x4E>(send);           // exchange with lane^2
      d2[j] = (u2 ? c4[j + 2] : c4[j]) + recv;
    }
    const bool u1 = (dc & 1) != 0;
    v2f send = u1 ? d2[0] : d2[1];
    v2f recv = dpp2<0xB1>(send);             // exchange with lane^1
    v2f e = (u1 ? d2[1] : d2[0]) + recv;
    if (ASSIGN) { bp0[icb + dc] = e.x;  bp1[icb + dc] = e.y; }
    else        { bp0[icb + dc] += e.x; bp1[icb + dc] += e.y; }
  }
}

__global__ __launch_bounds__(256, 3) void caps_kernel(const float* __restrict__ x,
                                                      const uint4* __restrict__ Wt4,
                                                      float* __restrict__ out) {
  const int t  = threadIdx.x;
  const int nc = t >> 4;
  const int dc = t & 15;
  const int s0 = blockIdx.x * S;

  __shared__ float b_lds[S][16][33];             // +1 pad: nc-column reads conflict-free
  __shared__ __align__(16) float c_lds[16][72];  // c[n][2*ic+s]; 16B-aligned rows

  v2f uh2[32];
  v2f o2 = (v2f){0.f, 0.f};

  // ---- u_hat: uh2[ic] = {sum_id u_s0*W, sum_id u_s1*W}; round-0 sum fused ----
  const v2f* xu0 = (const v2f*)(x + (s0 + 0) * 256);  // block-uniform -> s_load
  const v2f* xu1 = (const v2f*)(x + (s0 + 1) * 256);
#pragma unroll
  for (int ic = 0; ic < 32; ++ic) {
    uint4 wv = Wt4[ic * 256 + t];  // 8 bf16 weights, coalesced dwordx4
    v2f wp0 = (v2f){bflo(wv.x), bfhi(wv.x)};
    v2f wp1 = (v2f){bflo(wv.y), bfhi(wv.y)};
    v2f wp2 = (v2f){bflo(wv.z), bfhi(wv.z)};
    v2f wp3 = (v2f){bflo(wv.w), bfhi(wv.w)};
    v2f a0 = xu0[ic * 4 + 0] * wp0;  // pk_fma chain, sample 0 (id-paired)
    a0 = __builtin_elementwise_fma(xu0[ic * 4 + 1], wp1, a0);
    a0 = __builtin_elementwise_fma(xu0[ic * 4 + 2], wp2, a0);
    a0 = __builtin_elementwise_fma(xu0[ic * 4 + 3], wp3, a0);
    v2f a1 = xu1[ic * 4 + 0] * wp0;  // sample 1
    a1 = __builtin_elementwise_fma(xu1[ic * 4 + 1], wp1, a1);
    a1 = __builtin_elementwise_fma(xu1[ic * 4 + 2], wp2, a1);
    a1 = __builtin_elementwise_fma(xu1[ic * 4 + 3], wp3, a1);
    v2f u = (v2f){a0.x + a0.y, a1.x + a1.y};
    uh2[ic] = u;
    o2 += u;
  }

  // ---- routing round 0: b = 0 => c = 1/16 ----
  {
    v2f v = squash2(o2 * (v2f){0.0625f, 0.0625f});
    b_update2<true>(v, uh2, dc, &b_lds[0][nc][0], &b_lds[1][nc][0]);
  }
  __syncthreads();

  // ---- rounds 1, 2 ----
#pragma unroll
  for (int r = 1; r < 3; ++r) {
    if (t < 64) {  // softmax over nc; thread (s = t>>5, ic = t&31) owns one column
      const int s = t >> 5, ic = t & 31;
      // no max-subtraction: |b| is bounded far below exp overflow, and
      // softmax is shift-invariant in exact arithmetic.
      float e[16];
      float sum = 0.f;
#pragma unroll
      for (int n = 0; n < 16; ++n) { e[n] = __expf(b_lds[s][n][ic]); sum += e[n]; }
      const float inv = __builtin_amdgcn_rcpf(sum);
#pragma unroll
      for (int n = 0; n < 16; ++n) c_lds[n][2 * ic + s] = e[n] * inv;
    }
    __syncthreads();

    const float4* cp = (const float4*)&c_lds[nc][0];  // {c0[2j],c1[2j],c0[2j+1],c1[2j+1]}
    v2f o = (v2f){0.f, 0.f};
#pragma unroll
    for (int j = 0; j < 16; ++j) {
      float4 cc = cp[j];
      o = __builtin_elementwise_fma((v2f){cc.x, cc.y}, uh2[2 * j + 0], o);
      o = __builtin_elementwise_fma((v2f){cc.z, cc.w}, uh2[2 * j + 1], o);
    }
    v2f v = squash2(o);
    if (r == 2) {
      out[(s0 + 0) * 256 + t] = v.x;
      out[(s0 + 1) * 256 + t] = v.y;
    } else {
      b_update2<false>(v, uh2, dc, &b_lds[0][nc][0], &b_lds[1][nc][0]);
      __syncthreads();  // b complete before round-2 softmax reads it
    }
  }
}

extern "C" void kernel_launch(void* const* d_in, const int* in_sizes, int n_in,
                              void* d_out, int out_size, void* d_ws, size_t ws_size,
                              hipStream_t stream) {
  const float* x = (const float*)d_in[0];
  const float* W = (const float*)d_in[1];
  unsigned short* Wt = (unsigned short*)d_ws;  // 128 KB scratch (bf16 W-transpose)

  wt_kernel<<<256, 256, 0, stream>>>(W, Wt);
  caps_kernel<<<8192 / S, 256, 0, stream>>>(x, (const uint4*)Wt, (float*)d_out);
}